// Round 10
// baseline (92.651 us; speedup 1.0000x reference)
//
#include <hip/hip_runtime.h>

#define N_NODES 50000
#define N_EDGES 640000
#define IN_FEAT 128
#define OUT_FEAT 128
#define CAP 48            // bucket capacity/node; Poisson(12.8) -> P(deg>=48) ~ 1e-13
#define NBINS 49          // dst>>10 -> 0..48
#define NBINS_PAD 56      // multiple of 8 so bin%8 == blockIdx%8
#define BINCAP 16384      // entries per bin (max load ~13.8K at +6 sigma)
#define GEMM_BLOCKS 640
#define FILL_BLOCKS 625   // 625 * 256 * 4 edges = 640000
#define FUSED_BLOCKS (GEMM_BLOCKS + FILL_BLOCKS)

typedef unsigned int u32;
typedef unsigned short u16t;
typedef __attribute__((ext_vector_type(8))) short bf16x8;
typedef __attribute__((ext_vector_type(4))) float f32x4;

__device__ __forceinline__ u16t f2bf(float f) {
    union { float f; u32 u; } v; v.f = f;
    u32 r = (v.u + 0x7fffu + ((v.u >> 16) & 1u)) >> 16;
    return (u16t)r;
}
__device__ __forceinline__ float blo(u32 p) {
    union { u32 u; float f; } v; v.u = p << 16; return v.f;
}
__device__ __forceinline__ float bhi(u32 p) {
    union { u32 u; float f; } v; v.u = p & 0xffff0000u; return v.f;
}

__global__ __launch_bounds__(256) void k_zero(int* __restrict__ cnt,
                                              int* __restrict__ cursor) {
    int i = blockIdx.x * 256 + threadIdx.x;
    if (i < N_NODES) cnt[i] = 0;
    if (i < 64) cursor[i] = 0;
}

// Fused: blocks [0,GEMM_BLOCKS) = Y=F@W + relu-half; rest = edge binning (phase A).
__global__ __launch_bounds__(256) void k_fused(const float* __restrict__ feats,
                                               const float* __restrict__ weight,
                                               const int* __restrict__ edges,
                                               u16t* __restrict__ Ybf,
                                               float* __restrict__ out,
                                               int* __restrict__ cursor,
                                               u32* __restrict__ binbuf) {
    __shared__ u16t Wl[IN_FEAT * OUT_FEAT];   // 32 KB; fill role aliases a slice
    int tid = threadIdx.x;
    if (blockIdx.x >= GEMM_BLOCKS) {
        // ---- phase A: bin edges by dst>>10, append packed (dst,src) ----
        int* sh = (int*)Wl;        // sh[0..63]=hist, sh[64..127]=base, sh[128..191]=cur2
        int t = (blockIdx.x - GEMM_BLOCKS) * 256 + tid;
        int e0 = t * 4;
        int4 d4 = *reinterpret_cast<const int4*>(edges + e0);
        int4 s4 = *reinterpret_cast<const int4*>(edges + N_EDGES + e0);
        if (tid < 192) sh[tid] = 0;
        __syncthreads();
        int b0 = d4.x >> 10, b1 = d4.y >> 10, b2 = d4.z >> 10, b3 = d4.w >> 10;
        atomicAdd(&sh[b0], 1); atomicAdd(&sh[b1], 1);
        atomicAdd(&sh[b2], 1); atomicAdd(&sh[b3], 1);
        __syncthreads();
        if (tid < 64) {
            int h = sh[tid];
            sh[64 + tid] = h ? atomicAdd(&cursor[tid], h) : 0;
            sh[128 + tid] = 0;
        }
        __syncthreads();
        int o0 = atomicAdd(&sh[128 + b0], 1);
        binbuf[(b0 << 14) + sh[64 + b0] + o0] = ((u32)d4.x << 16) | (u32)s4.x;
        int o1 = atomicAdd(&sh[128 + b1], 1);
        binbuf[(b1 << 14) + sh[64 + b1] + o1] = ((u32)d4.y << 16) | (u32)s4.y;
        int o2 = atomicAdd(&sh[128 + b2], 1);
        binbuf[(b2 << 14) + sh[64 + b2] + o2] = ((u32)d4.z << 16) | (u32)s4.z;
        int o3 = atomicAdd(&sh[128 + b3], 1);
        binbuf[(b3 << 14) + sh[64 + b3] + o3] = ((u32)d4.w << 16) | (u32)s4.w;
        return;
    }
    // ---- gemm role ----
    for (int i = tid; i < IN_FEAT * (OUT_FEAT / 2); i += 256) {
        int k = i >> 6, np = i & 63;
        float2 w = *reinterpret_cast<const float2*>(weight + k * OUT_FEAT + 2 * np);
        u32 p = (u32)f2bf(w.x) | ((u32)f2bf(w.y) << 16);
        *reinterpret_cast<u32*>(&Wl[k * OUT_FEAT + 2 * np]) = p;
    }
    __syncthreads();
    int wid = tid >> 6, lane = tid & 63;
    int ncol0 = wid * 32;
    int krow = lane >> 4;
    int nl = lane & 15;
    bf16x8 bfrag[4][2];
    #pragma unroll
    for (int kb = 0; kb < 4; ++kb) {
        #pragma unroll
        for (int nt = 0; nt < 2; ++nt) {
            bf16x8 b;
            #pragma unroll
            for (int j = 0; j < 8; ++j) {
                int k = kb * 32 + krow * 8 + j;
                b[j] = (short)Wl[k * OUT_FEAT + ncol0 + nt * 16 + nl];
            }
            bfrag[kb][nt] = b;
        }
    }
    for (int mt = blockIdx.x; mt < N_NODES / 16; mt += GEMM_BLOCKS) {
        const float* arow = feats + (size_t)(mt * 16 + nl) * IN_FEAT + krow * 8;
        f32x4 acc0 = {0.f, 0.f, 0.f, 0.f};
        f32x4 acc1 = {0.f, 0.f, 0.f, 0.f};
        #pragma unroll
        for (int kb = 0; kb < 4; ++kb) {
            float4 a0 = *reinterpret_cast<const float4*>(arow + kb * 32);
            float4 a1 = *reinterpret_cast<const float4*>(arow + kb * 32 + 4);
            bf16x8 a;
            a[0] = (short)f2bf(a0.x); a[1] = (short)f2bf(a0.y);
            a[2] = (short)f2bf(a0.z); a[3] = (short)f2bf(a0.w);
            a[4] = (short)f2bf(a1.x); a[5] = (short)f2bf(a1.y);
            a[6] = (short)f2bf(a1.z); a[7] = (short)f2bf(a1.w);
            acc0 = __builtin_amdgcn_mfma_f32_16x16x32_bf16(a, bfrag[kb][0], acc0, 0, 0, 0);
            acc1 = __builtin_amdgcn_mfma_f32_16x16x32_bf16(a, bfrag[kb][1], acc1, 0, 0, 0);
        }
        #pragma unroll
        for (int r = 0; r < 4; ++r) {
            int node = mt * 16 + krow * 4 + r;
            int c0 = ncol0 + nl, c1 = ncol0 + 16 + nl;
            float v0 = acc0[r], v1 = acc1[r];
            Ybf[(size_t)node * OUT_FEAT + c0] = f2bf(v0);
            Ybf[(size_t)node * OUT_FEAT + c1] = f2bf(v1);
            out[(size_t)node * (2 * OUT_FEAT) + c0] = fmaxf(v0, 0.f);
            out[(size_t)node * (2 * OUT_FEAT) + c1] = fmaxf(v1, 0.f);
        }
    }
}

// Phase B: per-bin bucket fill. bin = blockIdx%56 -> bin%8 == blockIdx%8 (XCD pin).
__global__ __launch_bounds__(256) void k_fillb(const u32* __restrict__ binbuf,
                                               const int* __restrict__ cursor,
                                               int* __restrict__ cnt,
                                               u16t* __restrict__ bucket) {
    int bin = blockIdx.x % NBINS_PAD;
    if (bin >= NBINS) return;
    int slice = blockIdx.x / NBINS_PAD;              // 0..13
    int nb = cursor[bin];
    int chunk = (nb + 13) / 14;
    int s = slice * chunk;
    int e = s + chunk; if (e > nb) e = nb;
    const u32* bb = binbuf + ((size_t)bin << 14);
    for (int j = s + threadIdx.x; j < e; j += 256) {
        u32 p = bb[j];
        int dst = (int)(p >> 16), src = (int)(p & 0xffffu);
        int pos = atomicAdd(&cnt[dst], 1);
        if (pos < CAP) bucket[dst * CAP + pos] = (u16t)src;
    }
}

// out[:, 128:] = relu(mean_{src} Ybf[src]); wave/node, half-waves alternate edges.
__global__ __launch_bounds__(256) void k_gather(const u16t* __restrict__ Ybf,
                                                const int* __restrict__ cnt,
                                                const u16t* __restrict__ bucket,
                                                float* __restrict__ out) {
    int tid = threadIdx.x;
    int wid = tid >> 6, lane = tid & 63;
    int half = lane >> 5, l5 = lane & 31;
    int gw = blockIdx.x * 4 + wid;
    int nw = gridDim.x * 4;
    for (int n = gw; n < N_NODES; n += nw) {
        int deg = cnt[n];
        int m = (deg < CAP) ? deg : CAP;
        const u16t* b = bucket + n * CAP;
        float s0 = 0.f, s1 = 0.f, s2 = 0.f, s3 = 0.f;
        int j = half;
        for (; j + 3 <= m; j += 4) {
            int sa = (int)b[j], sb = (int)b[j + 2];
            uint2 pa = *reinterpret_cast<const uint2*>(Ybf + (size_t)sa * OUT_FEAT + 4 * l5);
            uint2 pb = *reinterpret_cast<const uint2*>(Ybf + (size_t)sb * OUT_FEAT + 4 * l5);
            s0 += blo(pa.x) + blo(pb.x); s1 += bhi(pa.x) + bhi(pb.x);
            s2 += blo(pa.y) + blo(pb.y); s3 += bhi(pa.y) + bhi(pb.y);
        }
        for (; j < m; j += 2) {
            int sa = (int)b[j];
            uint2 pa = *reinterpret_cast<const uint2*>(Ybf + (size_t)sa * OUT_FEAT + 4 * l5);
            s0 += blo(pa.x); s1 += bhi(pa.x);
            s2 += blo(pa.y); s3 += bhi(pa.y);
        }
        s0 += __shfl_xor(s0, 32); s1 += __shfl_xor(s1, 32);
        s2 += __shfl_xor(s2, 32); s3 += __shfl_xor(s3, 32);
        if (half == 0) {
            float inv = (deg > 0) ? 1.f / (float)deg : 0.f;
            float4 r;
            r.x = fmaxf(s0 * inv, 0.f); r.y = fmaxf(s1 * inv, 0.f);
            r.z = fmaxf(s2 * inv, 0.f); r.w = fmaxf(s3 * inv, 0.f);
            *reinterpret_cast<float4*>(out + (size_t)n * (2 * OUT_FEAT) + OUT_FEAT + 4 * l5) = r;
        }
    }
}

extern "C" void kernel_launch(void* const* d_in, const int* in_sizes, int n_in,
                              void* d_out, int out_size, void* d_ws, size_t ws_size,
                              hipStream_t stream) {
    const float* feats  = (const float*)d_in[0];
    const int*   edges  = (const int*)d_in[1];
    const float* weight = (const float*)d_in[2];
    float* out = (float*)d_out;

    u16t* Ybf    = (u16t*)d_ws;                               // 12.8 MB
    int*  cnt    = (int*)(Ybf + (size_t)N_NODES * OUT_FEAT);  // 200 KB
    u16t* bucket = (u16t*)(cnt + N_NODES);                    // 4.8 MB
    int*  cursor = (int*)(bucket + (size_t)N_NODES * CAP);    // 256 B
    u32*  binbuf = (u32*)(cursor + 64);                       // 64*16384*4 = 4 MB

    hipLaunchKernelGGL(k_zero,   dim3((N_NODES + 255) / 256), dim3(256), 0, stream, cnt, cursor);
    hipLaunchKernelGGL(k_fused,  dim3(FUSED_BLOCKS), dim3(256), 0, stream,
                       feats, weight, edges, Ybf, out, cursor, binbuf);
    hipLaunchKernelGGL(k_fillb,  dim3(NBINS_PAD * 14), dim3(256), 0, stream,
                       binbuf, cursor, cnt, bucket);
    hipLaunchKernelGGL(k_gather, dim3(2048), dim3(256), 0, stream, Ybf, cnt, bucket, out);
}